// Round 4
// baseline (11421.899 us; speedup 1.0000x reference)
//
#include <hip/hip_runtime.h>
#include <hip/hip_cooperative_groups.h>

namespace cg = cooperative_groups;

#define VOCAB 5000
#define EMB   128
#define HID   512
#define STK   128
#define BSZ   128
#define TLEN  128
#define KZ    768   // EMB + STK + HID
#define NG    2048  // 4*HID

typedef short bf16x8 __attribute__((ext_vector_type(8)));
typedef float f32x4  __attribute__((ext_vector_type(4)));

// ---- manual bf16 (RNE) helpers: hi + lo decomposition of fp32 ----
__device__ __forceinline__ unsigned short f2bf(float v) {
  union { float f; unsigned u; } q; q.f = v;
  unsigned r = q.u + 0x7FFFu + ((q.u >> 16) & 1u);
  return (unsigned short)(r >> 16);
}
__device__ __forceinline__ float bf2f(unsigned short b) {
  union { unsigned u; float f; } q; q.u = ((unsigned)b) << 16;
  return q.f;
}
__device__ __forceinline__ void split_bf(float v, unsigned short* hi, unsigned short* lo) {
  unsigned short h = f2bf(v);
  *hi = h;
  *lo = f2bf(v - bf2f(h));
}
__device__ __forceinline__ float sigm(float x) { return 1.f / (1.f + expf(-x)); }

// ---------------- prologue: combined gate-interleaved weights, bf16 hi/lo ----------------
// row (4j+g) = [ W_ih[g*HID+j][0:256] | W_hh[g*HID+j][0:512] ]   (g: 0=i,1=f,2=g,3=o)
__global__ __launch_bounds__(256) void build_wc(
    const float* __restrict__ W_ih, const float* __restrict__ W_hh,
    const float* __restrict__ b_ih, const float* __restrict__ b_hh,
    unsigned short* __restrict__ Wh, unsigned short* __restrict__ Wl,
    float* __restrict__ bc) {
  int idx = blockIdx.x * 256 + threadIdx.x;
  if (idx >= NG * KZ) return;
  int rd = idx / KZ, col = idx % KZ;
  int j = rd >> 2, g = rd & 3;
  int rs = g * HID + j;
  float v = (col < EMB + STK) ? W_ih[rs * (EMB + STK) + col]
                              : W_hh[rs * HID + (col - (EMB + STK))];
  unsigned short hi, lo;
  split_bf(v, &hi, &lo);
  Wh[idx] = hi; Wl[idx] = lo;
  if (col == 0) bc[rd] = b_ih[rs] + b_hh[rs];
}

// ---------------- prologue: init state (ws is re-poisoned 0xAA before every call) ----------------
__global__ __launch_bounds__(256) void init_state(
    const int* __restrict__ x, const float* __restrict__ emb,
    unsigned short* __restrict__ z0h, unsigned short* __restrict__ z0l,
    float* __restrict__ c, float* __restrict__ s, float* __restrict__ accb) {
  int idx = blockIdx.x * 256 + threadIdx.x;
  if (idx < BSZ * KZ) {
    int b = idx / KZ, d = idx % KZ;
    float v;
    if (d < EMB)            v = emb[x[b] * EMB + d];
    else if (d < EMB + STK) v = 1.0f;
    else                    v = 0.0f;
    unsigned short hi, lo;
    split_bf(v, &hi, &lo);
    z0h[idx] = hi; z0l[idx] = lo;
    return;
  }
  idx -= BSZ * KZ;
  if (idx < BSZ * HID) { c[idx] = 0.f; return; }
  idx -= BSZ * HID;
  if (idx < BSZ * TLEN) { s[idx] = 0.f; return; }
  idx -= BSZ * TLEN;
  if (idx < BSZ) accb[idx] = 0.f;
}

// ---------------- persistent: 128 steps of [gates GEMM + cell | stack] with grid syncs ----------------
// grid(128 blocks, 128 thr = 2 waves).
// Phase G: block (cg = bid&31, bg = bid>>5): tile 32b x 64c, wave tile 32x32 = 2x2 mfma,
//          3 hi/lo products (hh, hl, lh; lo*lo ~2^-18 rel, dropped). Cell fused in epilogue.
// Phase S: block bid = batch b: pop/push/vals + scans + stack read, writes r/emb into next z.
__global__ __launch_bounds__(128) void persist(
    const unsigned short* __restrict__ Wh, const unsigned short* __restrict__ Wl,
    const float* __restrict__ bc,
    unsigned short* __restrict__ z0h, unsigned short* __restrict__ z0l,
    unsigned short* __restrict__ z1h, unsigned short* __restrict__ z1l,
    float* __restrict__ c, float* __restrict__ h32,
    float* __restrict__ s, float* __restrict__ V,
    const float* __restrict__ emb, const int* __restrict__ x,
    const float* __restrict__ Wpop, const float* __restrict__ bpop,
    const float* __restrict__ Wpush, const float* __restrict__ bpush,
    const float* __restrict__ Wval, const float* __restrict__ bval) {
  cg::grid_group grid = cg::this_grid();

  const int bid  = blockIdx.x;           // 0..127
  const int cgi  = bid & 31;             // col group
  const int bg   = bid >> 5;             // batch group
  const int tid  = threadIdx.x;
  const int lane = tid & 63, wid = tid >> 6;
  const int m    = lane & 15;            // frag row within 16-tile
  const int kq   = lane >> 4;            // k-quad 0..3
  const int b0   = bg * 32;
  const int c0   = cgi * 64 + wid * 32;

  __shared__ float gbuf[2][32][36];
  __shared__ float hb[HID];
  __shared__ float wred[TLEN];
  __shared__ float cross[4];

  for (int t = 0; t < TLEN; ++t) {
    const unsigned short* zch = (t & 1) ? z1h : z0h;
    const unsigned short* zcl = (t & 1) ? z1l : z0l;
    unsigned short* znh = (t & 1) ? z0h : z1h;
    unsigned short* znl = (t & 1) ? z0l : z1l;

    // ================= phase G: gates GEMM + LSTM cell =================
    {
      const unsigned short* za0  = zch + (b0 + m) * KZ;
      const unsigned short* za1  = zch + (b0 + 16 + m) * KZ;
      const unsigned short* zb0  = zcl + (b0 + m) * KZ;
      const unsigned short* zb1  = zcl + (b0 + 16 + m) * KZ;
      const unsigned short* wa0  = Wh + (c0 + m) * KZ;
      const unsigned short* wa1  = Wh + (c0 + 16 + m) * KZ;
      const unsigned short* wb0p = Wl + (c0 + m) * KZ;
      const unsigned short* wb1p = Wl + (c0 + 16 + m) * KZ;

      f32x4 acc[2][2];
#pragma unroll
      for (int i = 0; i < 2; ++i)
#pragma unroll
        for (int j = 0; j < 2; ++j) acc[i][j] = (f32x4){0.f, 0.f, 0.f, 0.f};

#pragma unroll 4
      for (int kk = 0; kk < KZ; kk += 32) {
        const int o = kk + kq * 8;
        bf16x8 a0h = *(const bf16x8*)(za0 + o);
        bf16x8 a1h = *(const bf16x8*)(za1 + o);
        bf16x8 a0l = *(const bf16x8*)(zb0 + o);
        bf16x8 a1l = *(const bf16x8*)(zb1 + o);
        bf16x8 b0h = *(const bf16x8*)(wa0 + o);
        bf16x8 b1h = *(const bf16x8*)(wa1 + o);
        bf16x8 b0l = *(const bf16x8*)(wb0p + o);
        bf16x8 b1l = *(const bf16x8*)(wb1p + o);
        acc[0][0] = __builtin_amdgcn_mfma_f32_16x16x32_bf16(a0h, b0h, acc[0][0], 0, 0, 0);
        acc[0][1] = __builtin_amdgcn_mfma_f32_16x16x32_bf16(a0h, b1h, acc[0][1], 0, 0, 0);
        acc[1][0] = __builtin_amdgcn_mfma_f32_16x16x32_bf16(a1h, b0h, acc[1][0], 0, 0, 0);
        acc[1][1] = __builtin_amdgcn_mfma_f32_16x16x32_bf16(a1h, b1h, acc[1][1], 0, 0, 0);
        acc[0][0] = __builtin_amdgcn_mfma_f32_16x16x32_bf16(a0h, b0l, acc[0][0], 0, 0, 0);
        acc[0][1] = __builtin_amdgcn_mfma_f32_16x16x32_bf16(a0h, b1l, acc[0][1], 0, 0, 0);
        acc[1][0] = __builtin_amdgcn_mfma_f32_16x16x32_bf16(a1h, b0l, acc[1][0], 0, 0, 0);
        acc[1][1] = __builtin_amdgcn_mfma_f32_16x16x32_bf16(a1h, b1l, acc[1][1], 0, 0, 0);
        acc[0][0] = __builtin_amdgcn_mfma_f32_16x16x32_bf16(a0l, b0h, acc[0][0], 0, 0, 0);
        acc[0][1] = __builtin_amdgcn_mfma_f32_16x16x32_bf16(a0l, b1h, acc[0][1], 0, 0, 0);
        acc[1][0] = __builtin_amdgcn_mfma_f32_16x16x32_bf16(a1l, b0h, acc[1][0], 0, 0, 0);
        acc[1][1] = __builtin_amdgcn_mfma_f32_16x16x32_bf16(a1l, b1h, acc[1][1], 0, 0, 0);
      }

      // transpose via LDS: D layout col = lane&15, row = (lane>>4)*4 + reg  [m89 mapping]
#pragma unroll
      for (int bt = 0; bt < 2; ++bt)
#pragma unroll
        for (int ct = 0; ct < 2; ++ct)
#pragma unroll
          for (int r = 0; r < 4; ++r)
            gbuf[wid][bt * 16 + kq * 4 + r][ct * 16 + m] = acc[bt][ct][r];
      __syncthreads();

      // LSTM cell: 4 cells per lane, within this wave's 32b x 8unit region
#pragma unroll
      for (int p = 0; p < 4; ++p) {
        int q   = p * 64 + lane;     // 0..255
        int b_l = q >> 3;            // 0..31
        int u_l = q & 7;             // 0..7
        float4 g4 = *(const float4*)&gbuf[wid][b_l][u_l * 4];
        int rowb = c0 + u_l * 4;
        float4 bb = *(const float4*)&bc[rowb];
        int gb = b0 + b_l;
        int j  = (c0 >> 2) + u_l;
        float gi = g4.x + bb.x, gf = g4.y + bb.y, gg = g4.z + bb.z, go = g4.w + bb.w;
        float si = sigm(gi), sf = sigm(gf), tg = tanhf(gg), so = sigm(go);
        float cn = sf * c[gb * HID + j] + si * tg;
        c[gb * HID + j] = cn;
        float h = so * tanhf(cn);
        h32[gb * HID + j] = h;
        unsigned short hh2, hl2;
        split_bf(h, &hh2, &hl2);
        znh[gb * KZ + (EMB + STK) + j] = hh2;
        znl[gb * KZ + (EMB + STK) + j] = hl2;
      }
    }

    __threadfence();
    grid.sync();
    __threadfence();

    // ================= phase S: stack update (block = batch) =================
    if (t < TLEN - 1) {
      const int b = bid;
      const float* hrow = h32 + b * HID;
      float4 h4 = ((const float4*)hrow)[tid];          // 128 thr x 16B = 512 floats
      ((float4*)hb)[tid] = h4;

      float4 wp4 = *(const float4*)&Wpop[tid * 4];
      float4 wq4 = *(const float4*)&Wpush[tid * 4];
      float p0 = h4.x * wp4.x + h4.y * wp4.y + h4.z * wp4.z + h4.w * wp4.w;
      float p1 = h4.x * wq4.x + h4.y * wq4.y + h4.z * wq4.z + h4.w * wq4.w;
#pragma unroll
      for (int off = 32; off > 0; off >>= 1) {
        p0 += __shfl_xor(p0, off);
        p1 += __shfl_xor(p1, off);
      }
      if (lane == 0) { cross[wid * 2] = p0; cross[wid * 2 + 1] = p1; }
      __syncthreads();                                 // also covers hb[] writes
      const float pop  = sigm(cross[0] + cross[2] + bpop[0]);
      const float push = sigm(cross[1] + cross[3] + bpush[0]);

      // vals[tid] = relu(W_val[tid] . h + b_val[tid])
      float va = 0.f;
      const float* wrow = Wval + tid * HID;
#pragma unroll 4
      for (int k = 0; k < HID; k += 4) {
        float4 w4 = *(const float4*)&wrow[k];
        float4 hh4 = *(const float4*)&hb[k];
        va = fmaf(hh4.x, w4.x, fmaf(hh4.y, w4.y, fmaf(hh4.z, w4.z, fmaf(hh4.w, w4.w, va))));
      }
      va = fmaxf(va + bval[tid], 0.f);

      // scan 1: inclusive cumsum of s
      const float sv = s[b * TLEN + tid];
      float v1 = sv;
#pragma unroll
      for (int off = 1; off < 64; off <<= 1) {
        float u = __shfl_up(v1, off);
        if (lane >= off) v1 += u;
      }
      __syncthreads();                      // all cross[] readers done before reuse
      if (lane == 63) cross[wid] = v1;
      __syncthreads();
      if (wid == 1) v1 += cross[0];
      const float tot1 = cross[0] + cross[1];
      const float suf = tot1 - v1;
      float nsv = fmaxf(sv - fmaxf(pop - suf, 0.f), 0.f);
      if (tid == t) nsv = push;

      // scan 2: inclusive cumsum of ns
      float v2 = nsv;
#pragma unroll
      for (int off = 1; off < 64; off <<= 1) {
        float u = __shfl_up(v2, off);
        if (lane >= off) v2 += u;
      }
      __syncthreads();
      if (lane == 63) cross[wid] = v2;
      __syncthreads();
      if (wid == 1) v2 += cross[0];
      const float tot2 = cross[0] + cross[1];
      const float suf2 = tot2 - v2;
      const float wv = fminf(nsv, fmaxf(1.f - suf2, 0.f));

      s[b * TLEN + tid] = nsv;
      V[((size_t)b * TLEN + t) * STK + tid] = va;
      wred[tid] = wv;
      __syncthreads();

      // r = sum_{i<=t} w_i * V[b,i,:]   (rows > t have w == 0 exactly)
      float r0 = 0.f, r1 = 0.f, r2 = 0.f, r3 = 0.f;
      const float* Vb = V + (size_t)b * TLEN * STK;
      int i = 0;
      for (; i + 4 <= t; i += 4) {
        r0 = fmaf(wred[i + 0], Vb[(i + 0) * STK + tid], r0);
        r1 = fmaf(wred[i + 1], Vb[(i + 1) * STK + tid], r1);
        r2 = fmaf(wred[i + 2], Vb[(i + 2) * STK + tid], r2);
        r3 = fmaf(wred[i + 3], Vb[(i + 3) * STK + tid], r3);
      }
      for (; i < t; ++i) r0 = fmaf(wred[i], Vb[i * STK + tid], r0);
      float racc = ((r0 + r1) + (r2 + r3)) + wred[t] * va;

      unsigned short rh, rl;
      split_bf(racc, &rh, &rl);
      znh[b * KZ + EMB + tid] = rh;
      znl[b * KZ + EMB + tid] = rl;
      int xv = x[(t + 1) * BSZ + b];
      unsigned short eh, el;
      split_bf(emb[xv * EMB + tid], &eh, &el);
      znh[b * KZ + tid] = eh;
      znl[b * KZ + tid] = el;
    }

    __threadfence();
    grid.sync();
    __threadfence();
  }
}

// ---------------- epilogue: sigmoid( relu(h@W_out^T+b_out) @ W_cls^T + b_cls ) ----------------
__global__ __launch_bounds__(256) void final_out(
    const float* __restrict__ h32, const float* __restrict__ Wout,
    const float* __restrict__ bout, const float* __restrict__ Wcls,
    float* __restrict__ accb) {
  __shared__ float HT[32][65];
  __shared__ float WTt[64][36];
  __shared__ float red2[32][8];
  const int cgx = blockIdx.x;
  const int bg = blockIdx.y;
  const int tid = threadIdx.x;
  const int bl = tid >> 3;
  const int ul = tid & 7;
  const int r  = tid >> 3;
  const int ci = (tid & 7) * 8;
  float a0 = 0.f, a1 = 0.f, a2 = 0.f, a3 = 0.f;
  for (int kc = 0; kc < HID; kc += 64) {
    float4 ha  = *(const float4*)&h32[(bg * 32 + r) * HID + kc + ci];
    float4 hb4 = *(const float4*)&h32[(bg * 32 + r) * HID + kc + ci + 4];
    int vrow = cgx * 32 + r;
    float4 wa = make_float4(0.f, 0.f, 0.f, 0.f), wb = make_float4(0.f, 0.f, 0.f, 0.f);
    if (vrow < VOCAB) {
      wa = *(const float4*)&Wout[vrow * HID + kc + ci];
      wb = *(const float4*)&Wout[vrow * HID + kc + ci + 4];
    }
    HT[r][ci + 0] = ha.x;  HT[r][ci + 1] = ha.y;  HT[r][ci + 2] = ha.z;  HT[r][ci + 3] = ha.w;
    HT[r][ci + 4] = hb4.x; HT[r][ci + 5] = hb4.y; HT[r][ci + 6] = hb4.z; HT[r][ci + 7] = hb4.w;
    WTt[ci + 0][r] = wa.x; WTt[ci + 1][r] = wa.y; WTt[ci + 2][r] = wa.z; WTt[ci + 3][r] = wa.w;
    WTt[ci + 4][r] = wb.x; WTt[ci + 5][r] = wb.y; WTt[ci + 6][r] = wb.z; WTt[ci + 7][r] = wb.w;
    __syncthreads();
#pragma unroll 16
    for (int k = 0; k < 64; ++k) {
      float hv = HT[bl][k];
      float4 wv = *(const float4*)&WTt[k][ul * 4];
      a0 = fmaf(hv, wv.x, a0);
      a1 = fmaf(hv, wv.y, a1);
      a2 = fmaf(hv, wv.z, a2);
      a3 = fmaf(hv, wv.w, a3);
    }
    __syncthreads();
  }
  const int v0 = cgx * 32 + ul * 4;
  float part = 0.f;
  if (v0 + 0 < VOCAB) part = fmaf(fmaxf(a0 + bout[v0 + 0], 0.f), Wcls[v0 + 0], part);
  if (v0 + 1 < VOCAB) part = fmaf(fmaxf(a1 + bout[v0 + 1], 0.f), Wcls[v0 + 1], part);
  if (v0 + 2 < VOCAB) part = fmaf(fmaxf(a2 + bout[v0 + 2], 0.f), Wcls[v0 + 2], part);
  if (v0 + 3 < VOCAB) part = fmaf(fmaxf(a3 + bout[v0 + 3], 0.f), Wcls[v0 + 3], part);
  red2[bl][ul] = part;
  __syncthreads();
  if (tid < 32) {
    float sum = 0.f;
#pragma unroll
    for (int qq = 0; qq < 8; ++qq) sum += red2[tid][qq];
    atomicAdd(&accb[bg * 32 + tid], sum);
  }
}

__global__ __launch_bounds__(128) void final_sig(
    const float* __restrict__ accb, const float* __restrict__ bcls,
    float* __restrict__ out) {
  int b = threadIdx.x;
  out[b] = sigm(accb[b] + bcls[0]);
}

extern "C" void kernel_launch(void* const* d_in, const int* in_sizes, int n_in,
                              void* d_out, int out_size, void* d_ws, size_t ws_size,
                              hipStream_t stream) {
  const int*   x      = (const int*)d_in[0];
  const float* emb    = (const float*)d_in[1];
  const float* W_ih   = (const float*)d_in[2];
  const float* b_ih   = (const float*)d_in[3];
  const float* W_hh   = (const float*)d_in[4];
  const float* b_hh   = (const float*)d_in[5];
  const float* W_out  = (const float*)d_in[6];
  const float* b_out  = (const float*)d_in[7];
  const float* W_push = (const float*)d_in[8];
  const float* b_push = (const float*)d_in[9];
  const float* W_pop  = (const float*)d_in[10];
  const float* b_pop  = (const float*)d_in[11];
  const float* W_val  = (const float*)d_in[12];
  const float* b_val  = (const float*)d_in[13];
  const float* W_cls  = (const float*)d_in[14];
  const float* b_cls  = (const float*)d_in[15];

  char* ws = (char*)d_ws;
  size_t off = 0;
  auto carve = [&](size_t bytes) { char* p = ws + off; off += bytes; return p; };
  unsigned short* Wh  = (unsigned short*)carve((size_t)NG * KZ * 2);     // 3.1 MB
  unsigned short* Wl  = (unsigned short*)carve((size_t)NG * KZ * 2);
  unsigned short* z0h = (unsigned short*)carve((size_t)BSZ * KZ * 2);
  unsigned short* z0l = (unsigned short*)carve((size_t)BSZ * KZ * 2);
  unsigned short* z1h = (unsigned short*)carve((size_t)BSZ * KZ * 2);
  unsigned short* z1l = (unsigned short*)carve((size_t)BSZ * KZ * 2);
  float* bc   = (float*)carve((size_t)NG * 4);
  float* h32  = (float*)carve((size_t)BSZ * HID * 4);
  float* c    = (float*)carve((size_t)BSZ * HID * 4);
  float* s    = (float*)carve((size_t)BSZ * TLEN * 4);
  float* accb = (float*)carve(2048);
  float* V    = (float*)carve((size_t)BSZ * TLEN * STK * 4);             // 8.4 MB

  build_wc<<<(NG * KZ + 255) / 256, 256, 0, stream>>>(W_ih, W_hh, b_ih, b_hh, Wh, Wl, bc);
  {
    int total = BSZ * KZ + BSZ * HID + BSZ * TLEN + BSZ;
    init_state<<<(total + 255) / 256, 256, 0, stream>>>(x, emb, z0h, z0l, c, s, accb);
  }

  {
    const unsigned short* Wh_c = Wh;
    const unsigned short* Wl_c = Wl;
    const float* bc_c = bc;
    void* kargs[] = {
      (void*)&Wh_c, (void*)&Wl_c, (void*)&bc_c,
      (void*)&z0h, (void*)&z0l, (void*)&z1h, (void*)&z1l,
      (void*)&c, (void*)&h32, (void*)&s, (void*)&V,
      (void*)&emb, (void*)&x,
      (void*)&W_pop, (void*)&b_pop,
      (void*)&W_push, (void*)&b_push,
      (void*)&W_val, (void*)&b_val
    };
    hipLaunchCooperativeKernel((void*)persist, dim3(128), dim3(128), kargs, 0, stream);
  }

  final_out<<<dim3((VOCAB + 31) / 32, 4), 256, 0, stream>>>(h32, W_out, b_out, W_cls, accb);
  final_sig<<<1, 128, 0, stream>>>(accb, b_cls, (float*)d_out);
}

// Round 5
// 4024.382 us; speedup vs baseline: 2.8382x; 2.8382x over previous
//
#include <hip/hip_runtime.h>

#define VOCAB 5000
#define EMB   128
#define HID   512
#define STK   128
#define BSZ   128
#define TLEN  128
#define KZ    768   // EMB + STK + HID
#define NG    2048  // 4*HID

typedef short bf16x8 __attribute__((ext_vector_type(8)));
typedef float f32x4  __attribute__((ext_vector_type(4)));

// ---- manual bf16 (RNE) helpers: hi + lo decomposition of fp32 ----
__device__ __forceinline__ unsigned short f2bf(float v) {
  union { float f; unsigned u; } q; q.f = v;
  unsigned r = q.u + 0x7FFFu + ((q.u >> 16) & 1u);
  return (unsigned short)(r >> 16);
}
__device__ __forceinline__ float bf2f(unsigned short b) {
  union { unsigned u; float f; } q; q.u = ((unsigned)b) << 16;
  return q.f;
}
__device__ __forceinline__ void split_bf(float v, unsigned short* hi, unsigned short* lo) {
  unsigned short h = f2bf(v);
  *hi = h;
  *lo = f2bf(v - bf2f(h));
}
__device__ __forceinline__ float sigm(float x) { return 1.f / (1.f + expf(-x)); }

// ---------------- prologue: combined gate-interleaved weights, bf16 hi/lo ----------------
// row (4j+g) = [ W_ih[g*HID+j][0:256] | W_hh[g*HID+j][0:512] ]   (g: 0=i,1=f,2=g,3=o)
__global__ __launch_bounds__(256) void build_wc(
    const float* __restrict__ W_ih, const float* __restrict__ W_hh,
    const float* __restrict__ b_ih, const float* __restrict__ b_hh,
    unsigned short* __restrict__ Wh, unsigned short* __restrict__ Wl,
    float* __restrict__ bc) {
  int idx = blockIdx.x * 256 + threadIdx.x;
  if (idx >= NG * KZ) return;
  int rd = idx / KZ, col = idx % KZ;
  int j = rd >> 2, g = rd & 3;
  int rs = g * HID + j;
  float v = (col < EMB + STK) ? W_ih[rs * (EMB + STK) + col]
                              : W_hh[rs * HID + (col - (EMB + STK))];
  unsigned short hi, lo;
  split_bf(v, &hi, &lo);
  Wh[idx] = hi; Wl[idx] = lo;
  if (col == 0) bc[rd] = b_ih[rs] + b_hh[rs];
}

// ---------------- prologue: init state (ws is re-poisoned 0xAA before every call) ----------------
__global__ __launch_bounds__(256) void init_state(
    const int* __restrict__ x, const float* __restrict__ emb,
    unsigned short* __restrict__ z0h, unsigned short* __restrict__ z0l,
    float* __restrict__ c, float* __restrict__ s, float* __restrict__ accb) {
  int idx = blockIdx.x * 256 + threadIdx.x;
  if (idx < BSZ * KZ) {
    int b = idx / KZ, d = idx % KZ;
    float v;
    if (d < EMB)            v = emb[x[b] * EMB + d];
    else if (d < EMB + STK) v = 1.0f;
    else                    v = 0.0f;
    unsigned short hi, lo;
    split_bf(v, &hi, &lo);
    z0h[idx] = hi; z0l[idx] = lo;
    return;
  }
  idx -= BSZ * KZ;
  if (idx < BSZ * HID) { c[idx] = 0.f; return; }
  idx -= BSZ * HID;
  if (idx < BSZ * TLEN) { s[idx] = 0.f; return; }
  idx -= BSZ * TLEN;
  if (idx < BSZ) accb[idx] = 0.f;
}

// ---------------- per-step: gates GEMM (bf16 hi/lo MFMA) fused with LSTM cell ----------------
// C[128 b][2048 g] = Z[128][768] . Wc^T
// grid(32 cgroups of 64 cols, 4 bgroups of 32 b), 128 thr = 2 waves.
// wave tile 32b x 32c = 2x2 mfma 16x16 tiles, 3 hi/lo products each (hh, hl, lh).
__global__ __launch_bounds__(128) void gates_mfma(
    const unsigned short* __restrict__ zh, const unsigned short* __restrict__ zl,
    unsigned short* __restrict__ znh, unsigned short* __restrict__ znl,
    const unsigned short* __restrict__ Wh, const unsigned short* __restrict__ Wl,
    const float* __restrict__ bc, float* __restrict__ c,
    float* __restrict__ h32) {
  const int cg = blockIdx.x;          // 0..31
  const int bg = blockIdx.y;          // 0..3
  const int tid = threadIdx.x;
  const int lane = tid & 63, wid = tid >> 6;  // 2 waves
  const int m  = lane & 15;           // frag row within 16-tile
  const int kq = lane >> 4;           // k-quad 0..3
  const int b0 = bg * 32;
  const int c0 = cg * 64 + wid * 32;

  const unsigned short* za0  = zh + (b0 + m) * KZ;
  const unsigned short* za1  = zh + (b0 + 16 + m) * KZ;
  const unsigned short* zb0  = zl + (b0 + m) * KZ;
  const unsigned short* zb1  = zl + (b0 + 16 + m) * KZ;
  const unsigned short* wa0  = Wh + (c0 + m) * KZ;
  const unsigned short* wa1  = Wh + (c0 + 16 + m) * KZ;
  const unsigned short* wb0p = Wl + (c0 + m) * KZ;
  const unsigned short* wb1p = Wl + (c0 + 16 + m) * KZ;

  f32x4 acc[2][2];
#pragma unroll
  for (int i = 0; i < 2; ++i)
#pragma unroll
    for (int j = 0; j < 2; ++j) acc[i][j] = (f32x4){0.f, 0.f, 0.f, 0.f};

#pragma unroll 4
  for (int kk = 0; kk < KZ; kk += 32) {
    const int o = kk + kq * 8;
    bf16x8 a0h = *(const bf16x8*)(za0 + o);
    bf16x8 a1h = *(const bf16x8*)(za1 + o);
    bf16x8 a0l = *(const bf16x8*)(zb0 + o);
    bf16x8 a1l = *(const bf16x8*)(zb1 + o);
    bf16x8 b0h = *(const bf16x8*)(wa0 + o);
    bf16x8 b1h = *(const bf16x8*)(wa1 + o);
    bf16x8 b0l = *(const bf16x8*)(wb0p + o);
    bf16x8 b1l = *(const bf16x8*)(wb1p + o);
    // hi*hi
    acc[0][0] = __builtin_amdgcn_mfma_f32_16x16x32_bf16(a0h, b0h, acc[0][0], 0, 0, 0);
    acc[0][1] = __builtin_amdgcn_mfma_f32_16x16x32_bf16(a0h, b1h, acc[0][1], 0, 0, 0);
    acc[1][0] = __builtin_amdgcn_mfma_f32_16x16x32_bf16(a1h, b0h, acc[1][0], 0, 0, 0);
    acc[1][1] = __builtin_amdgcn_mfma_f32_16x16x32_bf16(a1h, b1h, acc[1][1], 0, 0, 0);
    // hi*lo
    acc[0][0] = __builtin_amdgcn_mfma_f32_16x16x32_bf16(a0h, b0l, acc[0][0], 0, 0, 0);
    acc[0][1] = __builtin_amdgcn_mfma_f32_16x16x32_bf16(a0h, b1l, acc[0][1], 0, 0, 0);
    acc[1][0] = __builtin_amdgcn_mfma_f32_16x16x32_bf16(a1h, b0l, acc[1][0], 0, 0, 0);
    acc[1][1] = __builtin_amdgcn_mfma_f32_16x16x32_bf16(a1h, b1l, acc[1][1], 0, 0, 0);
    // lo*hi  (lo*lo ~ 2^-18 relative: below fp32 accumulation noise, dropped)
    acc[0][0] = __builtin_amdgcn_mfma_f32_16x16x32_bf16(a0l, b0h, acc[0][0], 0, 0, 0);
    acc[0][1] = __builtin_amdgcn_mfma_f32_16x16x32_bf16(a0l, b1h, acc[0][1], 0, 0, 0);
    acc[1][0] = __builtin_amdgcn_mfma_f32_16x16x32_bf16(a1l, b0h, acc[1][0], 0, 0, 0);
    acc[1][1] = __builtin_amdgcn_mfma_f32_16x16x32_bf16(a1l, b1h, acc[1][1], 0, 0, 0);
  }

  // transpose via LDS: D layout col = lane&15, row = (lane>>4)*4 + reg  [m89 mapping]
  __shared__ float gbuf[2][32][36];
#pragma unroll
  for (int bt = 0; bt < 2; ++bt)
#pragma unroll
    for (int ct = 0; ct < 2; ++ct)
#pragma unroll
      for (int r = 0; r < 4; ++r)
        gbuf[wid][bt * 16 + kq * 4 + r][ct * 16 + m] = acc[bt][ct][r];
  __syncthreads();

  // LSTM cell: 4 cells per lane, within this wave's 32b x 8unit region
#pragma unroll
  for (int p = 0; p < 4; ++p) {
    int q   = p * 64 + lane;     // 0..255
    int b_l = q >> 3;            // 0..31
    int u_l = q & 7;             // 0..7
    float4 g4 = *(const float4*)&gbuf[wid][b_l][u_l * 4];
    int rowb = c0 + u_l * 4;
    float4 bb = *(const float4*)&bc[rowb];
    int gb = b0 + b_l;
    int j  = (c0 >> 2) + u_l;
    float gi = g4.x + bb.x, gf = g4.y + bb.y, gg = g4.z + bb.z, go = g4.w + bb.w;
    float si = sigm(gi), sf = sigm(gf), tg = tanhf(gg), so = sigm(go);
    float cn = sf * c[gb * HID + j] + si * tg;
    c[gb * HID + j] = cn;
    float h = so * tanhf(cn);
    h32[gb * HID + j] = h;
    unsigned short hh, hl;
    split_bf(h, &hh, &hl);
    znh[gb * KZ + (EMB + STK) + j] = hh;
    znl[gb * KZ + (EMB + STK) + j] = hl;
  }
}

// ---------------- per-step: stack update (1 block / batch, 128 thr = 2 waves) ----------------
__global__ __launch_bounds__(128) void stack_step(
    const float* __restrict__ h32,
    unsigned short* __restrict__ znh, unsigned short* __restrict__ znl,
    const float* __restrict__ emb, const int* __restrict__ x,
    const float* __restrict__ Wpop, const float* __restrict__ bpop,
    const float* __restrict__ Wpush, const float* __restrict__ bpush,
    const float* __restrict__ Wval, const float* __restrict__ bval,
    float* __restrict__ s, float* __restrict__ V, int t) {
  const int b = blockIdx.x;
  const int tid = threadIdx.x;
  const int lane = tid & 63, wid = tid >> 6;
  __shared__ float hb[HID];
  __shared__ float wred[TLEN];
  __shared__ float cross[4];

  const float* hrow = h32 + b * HID;
  float4 h4 = ((const float4*)hrow)[tid];          // 128 thr x 16B = 512 floats
  ((float4*)hb)[tid] = h4;

  // pop / push logits: per-thread 4-elem partial, shfl reduce, cross-wave via LDS
  float4 wp4 = *(const float4*)&Wpop[tid * 4];
  float4 wq4 = *(const float4*)&Wpush[tid * 4];
  float p0 = h4.x * wp4.x + h4.y * wp4.y + h4.z * wp4.z + h4.w * wp4.w;
  float p1 = h4.x * wq4.x + h4.y * wq4.y + h4.z * wq4.z + h4.w * wq4.w;
#pragma unroll
  for (int off = 32; off > 0; off >>= 1) {
    p0 += __shfl_xor(p0, off);
    p1 += __shfl_xor(p1, off);
  }
  if (lane == 0) { cross[wid * 2] = p0; cross[wid * 2 + 1] = p1; }
  __syncthreads();                                 // also covers hb[] writes
  const float pop  = sigm(cross[0] + cross[2] + bpop[0]);
  const float push = sigm(cross[1] + cross[3] + bpush[0]);

  // vals[tid] = relu(W_val[tid] . h + b_val[tid])
  float va = 0.f;
  const float* wrow = Wval + tid * HID;
#pragma unroll 4
  for (int k = 0; k < HID; k += 4) {
    float4 w4 = *(const float4*)&wrow[k];
    float4 hh = *(const float4*)&hb[k];
    va = fmaf(hh.x, w4.x, fmaf(hh.y, w4.y, fmaf(hh.z, w4.z, fmaf(hh.w, w4.w, va))));
  }
  va = fmaxf(va + bval[tid], 0.f);

  // scan 1: inclusive cumsum of s
  const float sv = s[b * TLEN + tid];
  float v1 = sv;
#pragma unroll
  for (int off = 1; off < 64; off <<= 1) {
    float u = __shfl_up(v1, off);
    if (lane >= off) v1 += u;
  }
  __syncthreads();                      // all cross[] readers done before reuse
  if (lane == 63) cross[wid] = v1;
  __syncthreads();
  if (wid == 1) v1 += cross[0];
  const float tot1 = cross[0] + cross[1];
  const float suf = tot1 - v1;
  float nsv = fmaxf(sv - fmaxf(pop - suf, 0.f), 0.f);
  if (tid == t) nsv = push;

  // scan 2: inclusive cumsum of ns
  float v2 = nsv;
#pragma unroll
  for (int off = 1; off < 64; off <<= 1) {
    float u = __shfl_up(v2, off);
    if (lane >= off) v2 += u;
  }
  __syncthreads();
  if (lane == 63) cross[wid] = v2;
  __syncthreads();
  if (wid == 1) v2 += cross[0];
  const float tot2 = cross[0] + cross[1];
  const float suf2 = tot2 - v2;
  const float wv = fminf(nsv, fmaxf(1.f - suf2, 0.f));

  s[b * TLEN + tid] = nsv;
  V[((size_t)b * TLEN + t) * STK + tid] = va;
  wred[tid] = wv;
  __syncthreads();

  // r = sum_{i<=t} w_i * V[b,i,:]   (rows > t have w == 0 exactly)
  float r0 = 0.f, r1 = 0.f, r2 = 0.f, r3 = 0.f;
  const float* Vb = V + (size_t)b * TLEN * STK;
  int i = 0;
  for (; i + 4 <= t; i += 4) {
    r0 = fmaf(wred[i + 0], Vb[(i + 0) * STK + tid], r0);
    r1 = fmaf(wred[i + 1], Vb[(i + 1) * STK + tid], r1);
    r2 = fmaf(wred[i + 2], Vb[(i + 2) * STK + tid], r2);
    r3 = fmaf(wred[i + 3], Vb[(i + 3) * STK + tid], r3);
  }
  for (; i < t; ++i) r0 = fmaf(wred[i], Vb[i * STK + tid], r0);
  float racc = ((r0 + r1) + (r2 + r3)) + wred[t] * va;

  unsigned short rh, rl;
  split_bf(racc, &rh, &rl);
  znh[b * KZ + EMB + tid] = rh;
  znl[b * KZ + EMB + tid] = rl;
  int xv = x[(t + 1) * BSZ + b];
  unsigned short eh, el;
  split_bf(emb[xv * EMB + tid], &eh, &el);
  znh[b * KZ + tid] = eh;
  znl[b * KZ + tid] = el;
}

// ---------------- epilogue: sigmoid( relu(h@W_out^T+b_out) @ W_cls^T + b_cls ) ----------------
__global__ __launch_bounds__(256) void final_out(
    const float* __restrict__ h32, const float* __restrict__ Wout,
    const float* __restrict__ bout, const float* __restrict__ Wcls,
    float* __restrict__ accb) {
  __shared__ float HT[32][65];
  __shared__ float WTt[64][36];
  __shared__ float red2[32][8];
  const int cgx = blockIdx.x;
  const int bg = blockIdx.y;
  const int tid = threadIdx.x;
  const int bl = tid >> 3;
  const int ul = tid & 7;
  const int r  = tid >> 3;
  const int ci = (tid & 7) * 8;
  float a0 = 0.f, a1 = 0.f, a2 = 0.f, a3 = 0.f;
  for (int kc = 0; kc < HID; kc += 64) {
    float4 ha  = *(const float4*)&h32[(bg * 32 + r) * HID + kc + ci];
    float4 hb4 = *(const float4*)&h32[(bg * 32 + r) * HID + kc + ci + 4];
    int vrow = cgx * 32 + r;
    float4 wa = make_float4(0.f, 0.f, 0.f, 0.f), wb = make_float4(0.f, 0.f, 0.f, 0.f);
    if (vrow < VOCAB) {
      wa = *(const float4*)&Wout[vrow * HID + kc + ci];
      wb = *(const float4*)&Wout[vrow * HID + kc + ci + 4];
    }
    HT[r][ci + 0] = ha.x;  HT[r][ci + 1] = ha.y;  HT[r][ci + 2] = ha.z;  HT[r][ci + 3] = ha.w;
    HT[r][ci + 4] = hb4.x; HT[r][ci + 5] = hb4.y; HT[r][ci + 6] = hb4.z; HT[r][ci + 7] = hb4.w;
    WTt[ci + 0][r] = wa.x; WTt[ci + 1][r] = wa.y; WTt[ci + 2][r] = wa.z; WTt[ci + 3][r] = wa.w;
    WTt[ci + 4][r] = wb.x; WTt[ci + 5][r] = wb.y; WTt[ci + 6][r] = wb.z; WTt[ci + 7][r] = wb.w;
    __syncthreads();
#pragma unroll 16
    for (int k = 0; k < 64; ++k) {
      float hv = HT[bl][k];
      float4 wv = *(const float4*)&WTt[k][ul * 4];
      a0 = fmaf(hv, wv.x, a0);
      a1 = fmaf(hv, wv.y, a1);
      a2 = fmaf(hv, wv.z, a2);
      a3 = fmaf(hv, wv.w, a3);
    }
    __syncthreads();
  }
  const int v0 = cgx * 32 + ul * 4;
  float part = 0.f;
  if (v0 + 0 < VOCAB) part = fmaf(fmaxf(a0 + bout[v0 + 0], 0.f), Wcls[v0 + 0], part);
  if (v0 + 1 < VOCAB) part = fmaf(fmaxf(a1 + bout[v0 + 1], 0.f), Wcls[v0 + 1], part);
  if (v0 + 2 < VOCAB) part = fmaf(fmaxf(a2 + bout[v0 + 2], 0.f), Wcls[v0 + 2], part);
  if (v0 + 3 < VOCAB) part = fmaf(fmaxf(a3 + bout[v0 + 3], 0.f), Wcls[v0 + 3], part);
  red2[bl][ul] = part;
  __syncthreads();
  if (tid < 32) {
    float sum = 0.f;
#pragma unroll
    for (int qq = 0; qq < 8; ++qq) sum += red2[tid][qq];
    atomicAdd(&accb[bg * 32 + tid], sum);
  }
}

__global__ __launch_bounds__(128) void final_sig(
    const float* __restrict__ accb, const float* __restrict__ bcls,
    float* __restrict__ out) {
  int b = threadIdx.x;
  out[b] = sigm(accb[b] + bcls[0]);
}

extern "C" void kernel_launch(void* const* d_in, const int* in_sizes, int n_in,
                              void* d_out, int out_size, void* d_ws, size_t ws_size,
                              hipStream_t stream) {
  const int*   x      = (const int*)d_in[0];
  const float* emb    = (const float*)d_in[1];
  const float* W_ih   = (const float*)d_in[2];
  const float* b_ih   = (const float*)d_in[3];
  const float* W_hh   = (const float*)d_in[4];
  const float* b_hh   = (const float*)d_in[5];
  const float* W_out  = (const float*)d_in[6];
  const float* b_out  = (const float*)d_in[7];
  const float* W_push = (const float*)d_in[8];
  const float* b_push = (const float*)d_in[9];
  const float* W_pop  = (const float*)d_in[10];
  const float* b_pop  = (const float*)d_in[11];
  const float* W_val  = (const float*)d_in[12];
  const float* b_val  = (const float*)d_in[13];
  const float* W_cls  = (const float*)d_in[14];
  const float* b_cls  = (const float*)d_in[15];

  char* ws = (char*)d_ws;
  size_t off = 0;
  auto carve = [&](size_t bytes) { char* p = ws + off; off += bytes; return p; };
  unsigned short* Wh  = (unsigned short*)carve((size_t)NG * KZ * 2);     // 3.1 MB
  unsigned short* Wl  = (unsigned short*)carve((size_t)NG * KZ * 2);
  unsigned short* z0h = (unsigned short*)carve((size_t)BSZ * KZ * 2);
  unsigned short* z0l = (unsigned short*)carve((size_t)BSZ * KZ * 2);
  unsigned short* z1h = (unsigned short*)carve((size_t)BSZ * KZ * 2);
  unsigned short* z1l = (unsigned short*)carve((size_t)BSZ * KZ * 2);
  float* bc   = (float*)carve((size_t)NG * 4);
  float* h32  = (float*)carve((size_t)BSZ * HID * 4);
  float* c    = (float*)carve((size_t)BSZ * HID * 4);
  float* s    = (float*)carve((size_t)BSZ * TLEN * 4);
  float* accb = (float*)carve(2048);
  float* V    = (float*)carve((size_t)BSZ * TLEN * STK * 4);             // 8.4 MB

  unsigned short* zh[2] = { z0h, z1h };
  unsigned short* zl[2] = { z0l, z1l };

  build_wc<<<(NG * KZ + 255) / 256, 256, 0, stream>>>(W_ih, W_hh, b_ih, b_hh, Wh, Wl, bc);
  {
    int total = BSZ * KZ + BSZ * HID + BSZ * TLEN + BSZ;
    init_state<<<(total + 255) / 256, 256, 0, stream>>>(x, emb, z0h, z0l, c, s, accb);
  }
  for (int t = 0; t < TLEN; ++t) {
    int cur = t & 1, nxt = (t + 1) & 1;
    gates_mfma<<<dim3(32, 4), 128, 0, stream>>>(zh[cur], zl[cur], zh[nxt], zl[nxt],
                                                Wh, Wl, bc, c, h32);
    if (t < TLEN - 1)
      stack_step<<<BSZ, 128, 0, stream>>>(h32, zh[nxt], zl[nxt], emb, x,
                                          W_pop, b_pop, W_push, b_push,
                                          W_val, b_val, s, V, t);
  }
  final_out<<<dim3((VOCAB + 31) / 32, 4), 256, 0, stream>>>(h32, W_out, b_out, W_cls, accb);
  final_sig<<<1, 128, 0, stream>>>(accb, b_cls, (float*)d_out);
}